// Round 9
// baseline (3914.661 us; speedup 1.0000x reference)
//
#include <hip/hip_runtime.h>
#include <math.h>

#define NB 32      // batch
#define NS 64      // src len
#define NT 64      // trg len
#define NHD 1024   // dec hidden
#define NV 32000
#define NR 2016    // (NT-1)*NB
#define NCT 250    // 32000/128
#define RECB 64    // blocks in persistent recurrence kernel

typedef unsigned short u16;
typedef __bf16 bf16x8 __attribute__((ext_vector_type(8)));
typedef float f32x4 __attribute__((ext_vector_type(4)));
typedef unsigned u32x4 __attribute__((ext_vector_type(4)));
#define MFMA16 __builtin_amdgcn_mfma_f32_16x16x32_bf16

__device__ __forceinline__ float sigmf(float x) { return 1.f / (1.f + expf(-x)); }
__device__ __forceinline__ u16 f2bf(float f) {
  union { float f; unsigned u; } v; v.f = f;
  unsigned r = v.u + 0x7FFFu + ((v.u >> 16) & 1u);
  return (u16)(r >> 16);
}
__device__ __forceinline__ float bf2f(u16 h) {
  union { unsigned u; float f; } v; v.u = ((unsigned)h) << 16; return v.f;
}

// ---- coherent (cache-bypassing) loads/stores for cross-block data ----
__device__ __forceinline__ u32x4 ldg_coh(const void* p) {
  u32x4 v;
  asm volatile("global_load_dwordx4 %0, %1, off sc0 sc1" : "=v"(v) : "v"(p));
  return v;  // NOT valid until an explicit s_waitcnt vmcnt(0)
}
__device__ __forceinline__ void stg_coh_u32(void* p, unsigned v) {
  asm volatile("global_store_dword %0, %1, off sc0 sc1" :: "v"(p), "v"(v) : "memory");
}
__device__ __forceinline__ unsigned ldg_coh_u32_wait(const void* p) {
  unsigned v;
  asm volatile("global_load_dword %0, %1, off sc0 sc1\n\ts_waitcnt vmcnt(0)"
               : "=v"(v) : "v"(p) : "memory");
  return v;
}
__device__ __forceinline__ void vmwait0() {
  asm volatile("s_waitcnt vmcnt(0)" ::: "memory");
}

__global__ void init_flags_kernel(unsigned* flags) {
  if (threadIdx.x < RECB) flags[threadIdx.x] = 0u;
}

// ---------------- row compaction: valid rows (t+1 < trg_len) -> rowmap ----------------
__global__ void rowmap_kernel(const int* __restrict__ trg_lens,
                              unsigned* __restrict__ rowmap, unsigned* __restrict__ mcnt) {
  __shared__ unsigned P[32];
  int tid = threadIdx.x;
  for (int i = tid; i < 2048; i += 256) rowmap[i] = 0u;
  if (tid == 0) {
    unsigned acc = 0;
    for (int b = 0; b < 32; b++) {
      P[b] = acc;
      int L = trg_lens[b]; if (L > NT) L = NT;
      acc += (unsigned)(L - 1);
    }
    mcnt[0] = acc;
  }
  __syncthreads();
  for (int b = 0; b < 32; b++) {
    int L = trg_lens[b]; if (L > NT) L = NT;
    int Lb = L - 1;
    if (tid < Lb) rowmap[P[b] + tid] = (unsigned)(tid * 32 + b);
  }
}

// ---------------- gathers (emit bf16) ----------------
__global__ void gather_src_bf16(const int* tok, const float* emb, u16* out) {
  int idx = blockIdx.x * 256 + threadIdx.x;  // 2048*64
  if (idx >= 2048 * 64) return;
  int m = idx >> 6, c8 = (idx & 63) * 8;
  const float4* s = (const float4*)(emb + (size_t)tok[m] * 512 + c8);
  float4 a = s[0], b = s[1];
  union { u16 h[8]; uint4 v; } u;
  u.h[0]=f2bf(a.x); u.h[1]=f2bf(a.y); u.h[2]=f2bf(a.z); u.h[3]=f2bf(a.w);
  u.h[4]=f2bf(b.x); u.h[5]=f2bf(b.y); u.h[6]=f2bf(b.z); u.h[7]=f2bf(b.w);
  *(uint4*)(out + (size_t)m * 512 + c8) = u.v;
}

__global__ void gather_trg_bf16(const int* tok, const float* emb, u16* out) {
  int idx = blockIdx.x * 256 + threadIdx.x;  // NR*64
  if (idx >= NR * 64) return;
  int m = idx >> 6, c8 = (idx & 63) * 8;
  int t = m >> 5, b = m & 31;  // row m = t*32 + b
  int token = tok[b * NT + t];
  const float4* s = (const float4*)(emb + (size_t)token * 512 + c8);
  float4 a = s[0], bb = s[1];
  union { u16 h[8]; uint4 v; } u;
  u.h[0]=f2bf(a.x); u.h[1]=f2bf(a.y); u.h[2]=f2bf(a.z); u.h[3]=f2bf(a.w);
  u.h[4]=f2bf(bb.x); u.h[5]=f2bf(bb.y); u.h[6]=f2bf(bb.z); u.h[7]=f2bf(bb.w);
  *(uint4*)(out + (size_t)m * 512 + c8) = u.v;
}

// ---------------- f32 -> bf16 ----------------
__global__ void cvt_bf16_kernel(const float* __restrict__ in, u16* __restrict__ out, long n) {
  long i = ((long)blockIdx.x * 256 + threadIdx.x) * 8;
  if (i >= n) return;
  float4 a = *(const float4*)(in + i);
  float4 b = *(const float4*)(in + i + 4);
  union { u16 h[8]; uint4 v; } u;
  u.h[0]=f2bf(a.x); u.h[1]=f2bf(a.y); u.h[2]=f2bf(a.z); u.h[3]=f2bf(a.w);
  u.h[4]=f2bf(b.x); u.h[5]=f2bf(b.y); u.h[6]=f2bf(b.z); u.h[7]=f2bf(b.w);
  *(uint4*)(out + i) = u.v;
}

// ---------------- dec W -> bf16 fragment layout ----------------
__global__ void cvt_dec_frag(const float* __restrict__ W, u16* __restrict__ out) {
  int idx = blockIdx.x * 256 + threadIdx.x;  // 524288 chunks
  if (idx >= 64 * 4 * 32 * 64) return;
  int lane = idx & 63;
  int kk = (idx >> 6) & 31;
  int g = (idx >> 11) & 3;
  int jt = idx >> 13;
  int row = g * 1024 + jt * 16 + (lane & 15);
  int col = kk * 32 + (lane >> 4) * 8;
  const float4* s = (const float4*)(W + (size_t)row * NHD + col);
  float4 a = s[0], b = s[1];
  union { u16 h[8]; uint4 v; } u;
  u.h[0]=f2bf(a.x); u.h[1]=f2bf(a.y); u.h[2]=f2bf(a.z); u.h[3]=f2bf(a.w);
  u.h[4]=f2bf(b.x); u.h[5]=f2bf(b.y); u.h[6]=f2bf(b.z); u.h[7]=f2bf(b.w);
  *(uint4*)(out + (size_t)idx * 8) = u.v;
}

// ---------------- bf16 MFMA GEMM for input gates (direct-global) ----------------
__global__ __launch_bounds__(256) void mfma_gemm_bias(
    const u16* __restrict__ A, const u16* __restrict__ Bm,
    const float* __restrict__ b0, const float* __restrict__ b1,
    float* __restrict__ C, int M, int N, int K) {
  int tid = threadIdx.x, wave = tid >> 6, lane = tid & 63;
  int r = lane & 15, q = lane >> 4;
  int mh = wave >> 1, nh = wave & 1;
  int rowbase = blockIdx.x * 128 + mh * 64;
  int colbase = blockIdx.y * 128 + nh * 64;
  f32x4 acc[4][4] = {};
  for (int k0 = 0; k0 < K; k0 += 32) {
    bf16x8 a[4], b[4];
#pragma unroll
    for (int mt = 0; mt < 4; mt++) {
      int rb = rowbase + mt * 16 + r;
      if (rb >= M) rb = 0;
      a[mt] = *(const bf16x8*)(A + (size_t)rb * K + k0 + q * 8);
    }
#pragma unroll
    for (int nt = 0; nt < 4; nt++)
      b[nt] = *(const bf16x8*)(Bm + (size_t)(colbase + nt * 16 + r) * K + k0 + q * 8);
#pragma unroll
    for (int mt = 0; mt < 4; mt++)
#pragma unroll
      for (int nt = 0; nt < 4; nt++)
        acc[mt][nt] = MFMA16(a[mt], b[nt], acc[mt][nt], 0, 0, 0);
  }
#pragma unroll
  for (int nt = 0; nt < 4; nt++) {
    int gn = colbase + nt * 16 + r;
    float bb = b0[gn] + b1[gn];
#pragma unroll
    for (int mt = 0; mt < 4; mt++)
#pragma unroll
      for (int j = 0; j < 4; j++) {
        int gm = rowbase + mt * 16 + q * 4 + j;
        if (gm < M) C[(size_t)gm * N + gn] = acc[mt][nt][j] + bb;
      }
  }
}

// ---------------- persistent recurrence (fence-free flag barrier, grouped) ----------------
#define ENC_H_OFF 65536
#define ENC_G_OFF 98304
#define DEC_G_OFF 65536
__global__ __launch_bounds__(256, 1) void recurrence_kernel(
    const u16* __restrict__ Wbf_e,    // [4096][512] (fwd 0..2047, rev 2048..)
    const u16* __restrict__ Wfragd,   // dec W fragment layout, 8MB
    const float* __restrict__ Aef, const float* __restrict__ Aer, const float* __restrict__ Ad,
    const int* __restrict__ src_lens,
    u16* __restrict__ ssb, float* __restrict__ hs_dec, u16* __restrict__ Ybf,
    u16* __restrict__ hbf_e,   // [2 parity][2 lstm][32][512] bf16 (coherent)
    u16* __restrict__ hbf_d,   // [2 parity][32][1024] bf16 (coherent)
    unsigned* flags) {
  __shared__ __align__(16) char smem[107008];
  const int tid = threadIdx.x, bid = blockIdx.x;
  const int wave = tid >> 6, lane = tid & 63;
  const int r = lane & 15, q = lane >> 4;
  const int g = wave;
  const int ob = tid >> 3;        // epilogue batch
  const int oj = (tid & 7) * 2;   // epilogue col pair within 16
  const int slen_ob = src_lens[ob];
  unsigned tgt = 0;

  // group barrier: this block signals flags[bid], waits on flags[fbase..fbase+fcnt)
#define FLAGBAR(fbase, fcnt)                                                        \
  do {                                                                              \
    tgt++;                                                                          \
    vmwait0();                                                                      \
    __syncthreads();                                                                \
    if (wave == 0) {                                                                \
      if (lane == 0) stg_coh_u32(flags + bid, tgt);                                 \
      unsigned fv = tgt;                                                            \
      do {                                                                          \
        if (lane < (fcnt)) fv = ldg_coh_u32_wait(flags + (fbase) + lane);           \
      } while (__any(fv < tgt));                                                    \
    }                                                                               \
    __syncthreads();                                                                \
  } while (0)

  // ================= encoder =================
  {
    const int lstm = bid >> 5, jt = bid & 31;
    float* gates = (float*)(smem + ENC_G_OFF);
    for (int c = tid; c < 64 * 64; c += 256) {
      int lr = c >> 6, c8 = (c & 63) * 8;
      int grow = lstm * 2048 + (lr >> 4) * 512 + jt * 16 + (lr & 15);
      uint4 v = *(const uint4*)(Wbf_e + (size_t)grow * 512 + c8);
      *(uint4*)(smem + ((lr * 1024 + c8 * 2) ^ ((lr & 7) << 4))) = v;
    }
    const float* Ae = lstm ? Aer : Aef;
    const int jcol = jt * 16 + oj;
    float creg0 = 0.f, creg1 = 0.f;
    for (int t = 0; t < NS; t++) {
      size_t abase = ((size_t)ob * NS + t) * 2048;
      float2 vi = *(const float2*)(Ae + abase + jcol);
      float2 vf = *(const float2*)(Ae + abase + 512 + jcol);
      float2 vg = *(const float2*)(Ae + abase + 1024 + jcol);
      float2 vo = *(const float2*)(Ae + abase + 1536 + jcol);
      if (t == 0) {
        u32x4 z = {0u, 0u, 0u, 0u};
#pragma unroll
        for (int k = 0; k < 8; k++) {
          int c = tid + k * 256;
          int hr = c >> 6, seg = c & 63;
          *(u32x4*)(smem + (ENC_H_OFF + ((hr * 1024 + seg * 16) ^ ((hr & 7) << 4)))) = z;
        }
      } else {
        const u16* hsrc = hbf_e + ((size_t)(t & 1) * 2 + lstm) * 16384;
        u32x4 hv[8];
#pragma unroll
        for (int k = 0; k < 8; k++) hv[k] = ldg_coh(hsrc + (tid + k * 256) * 8);
        vmwait0();
#pragma unroll
        for (int k = 0; k < 8; k++) {
          int c = tid + k * 256;
          int hr = c >> 6, seg = c & 63;
          *(u32x4*)(smem + (ENC_H_OFF + ((hr * 1024 + seg * 16) ^ ((hr & 7) << 4)))) = hv[k];
        }
      }
      __syncthreads();
      f32x4 acc0 = {0.f,0.f,0.f,0.f}, acc1 = {0.f,0.f,0.f,0.f};
      for (int ks = 0; ks < 512; ks += 32) {
        int col2 = (ks + q * 8) * 2;
        int a0r = r, a1r = 16 + r, br = g * 16 + r;
        bf16x8 a0 = *(const bf16x8*)(smem + (ENC_H_OFF + ((a0r * 1024 + col2) ^ ((a0r & 7) << 4))));
        bf16x8 a1 = *(const bf16x8*)(smem + (ENC_H_OFF + ((a1r * 1024 + col2) ^ ((a1r & 7) << 4))));
        bf16x8 bf = *(const bf16x8*)(smem + ((br * 1024 + col2) ^ ((br & 7) << 4)));
        acc0 = MFMA16(a0, bf, acc0, 0, 0, 0);
        acc1 = MFMA16(a1, bf, acc1, 0, 0, 0);
      }
#pragma unroll
      for (int j = 0; j < 4; j++) {
        gates[(g * 32 + q * 4 + j) * 17 + r] = acc0[j];
        gates[(g * 32 + 16 + q * 4 + j) * 17 + r] = acc1[j];
      }
      __syncthreads();
      {
        float I0 = vi.x + gates[(0 * 32 + ob) * 17 + oj];
        float I1 = vi.y + gates[(0 * 32 + ob) * 17 + oj + 1];
        float F0 = vf.x + gates[(1 * 32 + ob) * 17 + oj];
        float F1 = vf.y + gates[(1 * 32 + ob) * 17 + oj + 1];
        float G0 = vg.x + gates[(2 * 32 + ob) * 17 + oj];
        float G1 = vg.y + gates[(2 * 32 + ob) * 17 + oj + 1];
        float O0 = vo.x + gates[(3 * 32 + ob) * 17 + oj];
        float O1 = vo.y + gates[(3 * 32 + ob) * 17 + oj + 1];
        float c0 = sigmf(F0) * creg0 + sigmf(I0) * tanhf(G0);
        float c1 = sigmf(F1) * creg1 + sigmf(I1) * tanhf(G1);
        float h0 = sigmf(O0) * tanhf(c0);
        float h1 = sigmf(O1) * tanhf(c1);
        creg0 = c0; creg1 = c1;
        unsigned hv2 = ((unsigned)f2bf(h1) << 16) | f2bf(h0);
        stg_coh_u32(hbf_e + ((size_t)((t + 1) & 1) * 2 + lstm) * 16384 + ob * 512 + jcol, hv2);
        *(unsigned*)(ssb + ((size_t)ob * NS + t) * NHD + lstm * 512 + jcol) = hv2;
        if (t == slen_ob - 1)
          stg_coh_u32(hbf_d + ob * NHD + lstm * 512 + jcol, hv2);
      }
      FLAGBAR(lstm * 32, 32);  // enc blocks only depend on same-lstm peers
    }
  }

  // phase barrier: all encoder output (hbf_d) visible to every block
  FLAGBAR(0, RECB);

  // ================= decoder =================
  {
    const int jt = bid;
    const int jcol = jt * 16 + oj;
    float* gates = (float*)(smem + DEC_G_OFF);
    const u16* wbase = Wfragd + (size_t)(jt * 4 + g) * 16384;
    float cd0 = 0.f, cd1 = 0.f;
    for (int t = 0; t < NT - 1; t++) {
      const float* ad = Ad + ((size_t)t * NB + ob) * 4096;
      float2 vi = *(const float2*)(ad + jcol);
      float2 vf = *(const float2*)(ad + 1024 + jcol);
      float2 vg = *(const float2*)(ad + 2048 + jcol);
      float2 vo = *(const float2*)(ad + 3072 + jcol);
      const u16* hsrc = hbf_d + (size_t)(t & 1) * (32 * NHD);
      {
        u32x4 hv[16];
#pragma unroll
        for (int k = 0; k < 16; k++) hv[k] = ldg_coh(hsrc + (tid + k * 256) * 8);
        vmwait0();
#pragma unroll
        for (int k = 0; k < 16; k++) {
          int c = tid + k * 256;
          int hr = c >> 7, seg = c & 127;
          *(u32x4*)(smem + ((hr * 2048 + seg * 16) ^ ((hr & 7) << 4))) = hv[k];
        }
      }
      __syncthreads();
      f32x4 acc0 = {0.f,0.f,0.f,0.f}, acc1 = {0.f,0.f,0.f,0.f};
      for (int kk = 0; kk < 32; kk++) {
        int colb = (kk * 32 + q * 8) * 2;
        int a0r = r, a1r = 16 + r;
        bf16x8 a0 = *(const bf16x8*)(smem + ((a0r * 2048 + colb) ^ ((a0r & 7) << 4)));
        bf16x8 a1 = *(const bf16x8*)(smem + ((a1r * 2048 + colb) ^ ((a1r & 7) << 4)));
        bf16x8 bf = *(const bf16x8*)(wbase + ((size_t)kk * 64 + lane) * 8);
        acc0 = MFMA16(a0, bf, acc0, 0, 0, 0);
        acc1 = MFMA16(a1, bf, acc1, 0, 0, 0);
      }
#pragma unroll
      for (int j = 0; j < 4; j++) {
        gates[(g * 32 + q * 4 + j) * 17 + r] = acc0[j];
        gates[(g * 32 + 16 + q * 4 + j) * 17 + r] = acc1[j];
      }
      __syncthreads();
      {
        float I0 = vi.x + gates[(0 * 32 + ob) * 17 + oj];
        float I1 = vi.y + gates[(0 * 32 + ob) * 17 + oj + 1];
        float F0 = vf.x + gates[(1 * 32 + ob) * 17 + oj];
        float F1 = vf.y + gates[(1 * 32 + ob) * 17 + oj + 1];
        float G0 = vg.x + gates[(2 * 32 + ob) * 17 + oj];
        float G1 = vg.y + gates[(2 * 32 + ob) * 17 + oj + 1];
        float O0 = vo.x + gates[(3 * 32 + ob) * 17 + oj];
        float O1 = vo.y + gates[(3 * 32 + ob) * 17 + oj + 1];
        float c0 = sigmf(F0) * cd0 + sigmf(I0) * tanhf(G0);
        float c1 = sigmf(F1) * cd1 + sigmf(I1) * tanhf(G1);
        float h0 = sigmf(O0) * tanhf(c0);
        float h1 = sigmf(O1) * tanhf(c1);
        cd0 = c0; cd1 = c1;
        size_t rowY = (size_t)t * NB + ob;
        unsigned hv2 = ((unsigned)f2bf(h1) << 16) | f2bf(h0);
        stg_coh_u32(hbf_d + (size_t)((t + 1) & 1) * (32 * NHD) + ob * NHD + jcol, hv2);
        *(unsigned*)(Ybf + rowY * 2048 + jcol) = hv2;
        float2 hvf; hvf.x = h0; hvf.y = h1;
        *(float2*)(hs_dec + rowY * NHD + jcol) = hvf;
      }
      if (t != NT - 2) FLAGBAR(0, RECB);
    }
  }
#undef FLAGBAR
}

// ---------------- batched attention (bf16 src states, compact rows) ----------------
__global__ __launch_bounds__(256) void attn_kernel(const float* __restrict__ hs,
                                                   const u16* __restrict__ ssb,
                                                   const int* __restrict__ src_lens,
                                                   const unsigned* __restrict__ rowmap,
                                                   const unsigned* __restrict__ mcnt,
                                                   u16* __restrict__ Ybf) {
  __shared__ __align__(16) float hsh[NHD];
  __shared__ float sc[NS];
  __shared__ float att[NS];
  int cr = blockIdx.x;
  if ((unsigned)cr >= mcnt[0]) return;
  int rr = (int)rowmap[cr];
  int b = rr & 31;
  int tid = threadIdx.x;
  for (int i = tid; i < NHD; i += 256) hsh[i] = hs[(size_t)rr * NHD + i];
  __syncthreads();
  {
    int s = tid >> 2, q = tid & 3;
    const u16* row = ssb + ((size_t)b * NS + s) * NHD + q * 256;
    const float* h4 = hsh + q * 256;
    float p = 0.f;
    for (int k = 0; k < 256; k += 8) {
      uint4 v = *(const uint4*)(row + k);
      p += h4[k + 0] * bf2f((u16)(v.x & 0xFFFF)) + h4[k + 1] * bf2f((u16)(v.x >> 16));
      p += h4[k + 2] * bf2f((u16)(v.y & 0xFFFF)) + h4[k + 3] * bf2f((u16)(v.y >> 16));
      p += h4[k + 4] * bf2f((u16)(v.z & 0xFFFF)) + h4[k + 5] * bf2f((u16)(v.z >> 16));
      p += h4[k + 6] * bf2f((u16)(v.w & 0xFFFF)) + h4[k + 7] * bf2f((u16)(v.w >> 16));
    }
    p += __shfl_xor(p, 1);
    p += __shfl_xor(p, 2);
    if (q == 0) sc[s] = (s < src_lens[b]) ? p : -1e9f;
  }
  __syncthreads();
  if (tid < 64) {
    float v = sc[tid];
    float m = v;
#pragma unroll
    for (int off = 1; off < 64; off <<= 1) m = fmaxf(m, __shfl_xor(m, off));
    float e = expf(v - m);
    float ssum = e;
#pragma unroll
    for (int off = 1; off < 64; off <<= 1) ssum += __shfl_xor(ssum, off);
    att[tid] = e / ssum;
  }
  __syncthreads();
  float a0 = 0, a1 = 0, a2 = 0, a3 = 0;
  int d = tid * 4;
  for (int s2 = 0; s2 < NS; s2++) {
    float a = att[s2];
    uint2 v = *(const uint2*)(ssb + ((size_t)b * NS + s2) * NHD + d);
    a0 += a * bf2f((u16)(v.x & 0xFFFF));
    a1 += a * bf2f((u16)(v.x >> 16));
    a2 += a * bf2f((u16)(v.y & 0xFFFF));
    a3 += a * bf2f((u16)(v.y >> 16));
  }
  ushort4 o;
  o.x = f2bf(a0); o.y = f2bf(a1); o.z = f2bf(a2); o.w = f2bf(a3);
  *(ushort4*)(Ybf + (size_t)rr * 2048 + NHD + d) = o;
}

// ---------------- MFMA logits GEMM (reg-staged LDS, swizzled, NO-SPILL bounds) + fused LSE ----------------
// 1D grid 4000 = 16 row-tiles x 250 col-tiles (XCD-grouped); blocks past M_valid exit early.
// __launch_bounds__(256, 2): cap occupancy target at 2 waves/EU so the register
// allocator keeps the 64-reg accumulator + staging regs WITHOUT spilling
// (R4/R6 regression root cause: VGPR capped at 72-92 -> acc spilled -> GBs of scratch traffic).
__global__ __launch_bounds__(256, 2) void gemmlse_mfma(
    const u16* __restrict__ Y,   // [2016][2048] bf16
    const u16* __restrict__ Wo,  // [32000][2048] bf16
    const float* __restrict__ bo, const int* __restrict__ trg_tok,
    const unsigned* __restrict__ rowmap, const unsigned* __restrict__ mcnt,
    float* __restrict__ pm, float* __restrict__ ps, float* __restrict__ tgtlog) {
  __shared__ __align__(16) u16 Ash[128 * 64];
  __shared__ __align__(16) u16 Bsh[128 * 64];
  __shared__ int tgtc[128];
  __shared__ float pmp[2][128];
  __shared__ float psp[2][128];
  int o = blockIdx.x;
  int u = (o & 7) * 500 + (o >> 3);
  int bm = u & 15, bn = u >> 4;
  const int M = (int)mcnt[0];
  if (bm * 128 >= M) return;   // compacted: skip fully-masked row tiles
  int tid = threadIdx.x;
  int wave = tid >> 6, lane = tid & 63;
  int r = lane & 15, q = lane >> 4;
  int mh = wave >> 1, nh = wave & 1;
  if (tid < 128) {
    int gm = bm * 128 + tid;
    if (gm < M) {
      int rr = (int)rowmap[gm];
      int tt = rr >> 5, b = rr & 31;
      tgtc[tid] = trg_tok[b * NT + tt + 1];
    } else {
      tgtc[tid] = -1;
    }
  }
  // staging geometry: chunk c = tid + i*256; row = c>>3 (0..127), seg = c&7 (16B of 128B row)
  const int srow = tid >> 3, sseg = tid & 7;
  size_t yoff[4], woff[4];
  int lds_b[4];
#pragma unroll
  for (int i = 0; i < 4; i++) {
    int row = srow + i * 32;
    int gm = bm * 128 + row;
    int ga = (gm < M) ? (int)rowmap[gm] : 0;  // invalid -> row 0 (always initialized)
    yoff[i] = (size_t)ga * 2048 + sseg * 8;
    woff[i] = (size_t)(bn * 128 + row) * 2048 + sseg * 8;
    lds_b[i] = (row * 128 + sseg * 16) ^ ((row & 7) << 4);  // write-side swizzle
  }
  f32x4 acc[4][4] = {};
  for (int k0 = 0; k0 < 2048; k0 += 64) {
    uint4 av[4], bv[4];
#pragma unroll
    for (int i = 0; i < 4; i++) {
      av[i] = *(const uint4*)(Y + yoff[i] + k0);   // issued before barrier: latency hides
      bv[i] = *(const uint4*)(Wo + woff[i] + k0);  // under previous tile's MFMA
    }
    __syncthreads();  // previous tile's ds_reads complete before overwrite
#pragma unroll
    for (int i = 0; i < 4; i++) {
      *(uint4*)((char*)Ash + lds_b[i]) = av[i];
      *(uint4*)((char*)Bsh + lds_b[i]) = bv[i];
    }
    __syncthreads();
#pragma unroll
    for (int ksub = 0; ksub < 2; ksub++) {
      bf16x8 a[4], b[4];
#pragma unroll
      for (int mt = 0; mt < 4; mt++) {
        int row = mh * 64 + mt * 16 + r;
        int byt = (row * 128 + (ksub * 4 + q) * 16) ^ ((row & 7) << 4);  // read-side swizzle
        a[mt] = *(const bf16x8*)((char*)Ash + byt);
      }
#pragma unroll
      for (int nt = 0; nt < 4; nt++) {
        int row = nh * 64 + nt * 16 + r;
        int byt = (row * 128 + (ksub * 4 + q) * 16) ^ ((row & 7) << 4);
        b[nt] = *(const bf16x8*)((char*)Bsh + byt);
      }
#pragma unroll
      for (int mt = 0; mt < 4; mt++)
#pragma unroll
        for (int nt = 0; nt < 4; nt++)
          acc[mt][nt] = MFMA16(a[mt], b[nt], acc[mt][nt], 0, 0, 0);
    }
  }
  // bias
  float bo4[4];
#pragma unroll
  for (int nt = 0; nt < 4; nt++) bo4[nt] = bo[bn * 128 + nh * 64 + nt * 16 + r];
#pragma unroll
  for (int mt = 0; mt < 4; mt++)
#pragma unroll
    for (int nt = 0; nt < 4; nt++)
#pragma unroll
      for (int j = 0; j < 4; j++) acc[mt][nt][j] += bo4[nt];
  __syncthreads();
  // in-register row-wise lse over this wave's 64 cols + target capture
#pragma unroll
  for (int mt = 0; mt < 4; mt++) {
#pragma unroll
    for (int j = 0; j < 4; j++) {
      float m = fmaxf(fmaxf(acc[mt][0][j], acc[mt][1][j]), fmaxf(acc[mt][2][j], acc[mt][3][j]));
      m = fmaxf(m, __shfl_xor(m, 1));
      m = fmaxf(m, __shfl_xor(m, 2));
      m = fmaxf(m, __shfl_xor(m, 4));
      m = fmaxf(m, __shfl_xor(m, 8));
      float s = expf(acc[mt][0][j] - m) + expf(acc[mt][1][j] - m) +
                expf(acc[mt][2][j] - m) + expf(acc[mt][3][j] - m);
      s += __shfl_xor(s, 1);
      s += __shfl_xor(s, 2);
      s += __shfl_xor(s, 4);
      s += __shfl_xor(s, 8);
      int lrow = mh * 64 + mt * 16 + q * 4 + j;
      if (r == 0) { pmp[nh][lrow] = m; psp[nh][lrow] = s; }
      int tc = tgtc[lrow];
      int off = tc - (bn * 128 + nh * 64);
      if (off >= 0 && off < 64 && (off & 15) == r) {
        tgtlog[bm * 128 + lrow] = acc[mt][off >> 4][j];
      }
    }
  }
  __syncthreads();
  if (tid < 128) {
    int gm = bm * 128 + tid;
    if (gm < M) {
      float m0 = pmp[0][tid], m1 = pmp[1][tid];
      float m = fmaxf(m0, m1);
      float s = psp[0][tid] * expf(m0 - m) + psp[1][tid] * expf(m1 - m);
      pm[(size_t)bn * NR + gm] = m;
      ps[(size_t)bn * NR + gm] = s;
    }
  }
}

// ---------------- merge per-chunk lse partials (compact rows) ----------------
__global__ void lse_combine_kernel(const float* __restrict__ pm, const float* __restrict__ ps,
                                   const float* __restrict__ tgtlog,
                                   const unsigned* __restrict__ mcnt,
                                   float* __restrict__ rowval) {
  int cr = blockIdx.x * blockDim.x + threadIdx.x;
  if (cr >= NR) return;
  if ((unsigned)cr >= mcnt[0]) { rowval[cr] = 0.f; return; }
  float m = -1e30f;
  for (int i = 0; i < NCT; i++) m = fmaxf(m, pm[(size_t)i * NR + cr]);
  float s = 0.f;
  for (int i = 0; i < NCT; i++) s += ps[(size_t)i * NR + cr] * expf(pm[(size_t)i * NR + cr] - m);
  float lse = m + logf(s);
  rowval[cr] = tgtlog[cr] - lse;
}

__global__ void final_reduce_kernel(const float* __restrict__ rowval, float* __restrict__ out) {
  __shared__ float sm[256];
  float s = 0.f;
  for (int i = threadIdx.x; i < NR; i += 256) s += rowval[i];
  sm[threadIdx.x] = s;
  __syncthreads();
  for (int off = 128; off > 0; off >>= 1) {
    if (threadIdx.x < off) sm[threadIdx.x] += sm[threadIdx.x + off];
    __syncthreads();
  }
  if (threadIdx.x == 0) out[0] = sm[0];
}

extern "C" void kernel_launch(void* const* d_in, const int* in_sizes, int n_in,
                              void* d_out, int out_size, void* d_ws, size_t ws_size,
                              hipStream_t stream) {
  const int* src_tokens = (const int*)d_in[0];
  const int* src_lens = (const int*)d_in[1];
  const int* trg_tokens = (const int*)d_in[2];
  const int* trg_lens = (const int*)d_in[3];
  const float* src_emb = (const float*)d_in[4];
  const float* trg_emb = (const float*)d_in[5];
  const float* We_ih = (const float*)d_in[6];
  const float* We_hh = (const float*)d_in[7];
  const float* be_ih = (const float*)d_in[8];
  const float* be_hh = (const float*)d_in[9];
  const float* Wr_ih = (const float*)d_in[10];
  const float* Wr_hh = (const float*)d_in[11];
  const float* br_ih = (const float*)d_in[12];
  const float* br_hh = (const float*)d_in[13];
  const float* Wd_ih = (const float*)d_in[14];
  const float* Wd_hh = (const float*)d_in[15];
  const float* bd_ih = (const float*)d_in[16];
  const float* bd_hh = (const float*)d_in[17];
  const float* W_out = (const float*)d_in[18];
  const float* b_out = (const float*)d_in[19];

  char* base = (char*)d_ws;
  size_t off = 0;
  auto alloc = [&](size_t bytes) -> char* {
    char* p = base + off;
    off += (bytes + 255) & ~(size_t)255;
    return p;
  };
  u16* xsrcb = (u16*)alloc((size_t)2048 * 512 * 2);
  u16* xtrgb = (u16*)alloc((size_t)NR * 512 * 2);
  u16* Wihe = (u16*)alloc((size_t)2048 * 512 * 2);
  u16* Wihr = (u16*)alloc((size_t)2048 * 512 * 2);
  u16* Wihd = (u16*)alloc((size_t)4096 * 512 * 2);
  u16* Wbf_e = (u16*)alloc((size_t)4096 * 512 * 2);
  u16* Wfragd = (u16*)alloc((size_t)4096 * 1024 * 2);
  u16* Wobf = (u16*)alloc((size_t)NV * 2048 * 2);
  float* Aef = (float*)alloc((size_t)2048 * 2048 * 4);
  float* Aer = (float*)alloc((size_t)2048 * 2048 * 4);
  float* Ad  = (float*)alloc((size_t)NR * 4096 * 4);
  u16* ssb  = (u16*)alloc((size_t)NB * NS * NHD * 2);
  float* hs_dec = (float*)alloc((size_t)NR * NHD * 4);
  u16* Ybf = (u16*)alloc((size_t)NR * 2048 * 2);
  u16* hbf_e = (u16*)alloc((size_t)4 * 32 * 512 * 2);
  u16* hbf_d = (u16*)alloc((size_t)2 * 32 * NHD * 2);
  float* pm = (float*)alloc((size_t)NCT * NR * 4);
  float* ps = (float*)alloc((size_t)NCT * NR * 4);
  float* tgtlog = (float*)alloc((size_t)NR * 4);
  float* rowval = (float*)alloc((size_t)NR * 4);
  unsigned* flags = (unsigned*)alloc(256);
  unsigned* rowmap = (unsigned*)alloc(2048 * 4);
  unsigned* mcnt = (unsigned*)alloc(256);

  init_flags_kernel<<<1, 64, 0, stream>>>(flags);
  rowmap_kernel<<<1, 256, 0, stream>>>(trg_lens, rowmap, mcnt);

  // gathers (bf16 out)
  gather_src_bf16<<<512, 256, 0, stream>>>(src_tokens, src_emb, xsrcb);
  gather_trg_bf16<<<(NR * 64 + 255) / 256, 256, 0, stream>>>(trg_tokens, trg_emb, xtrgb);

  // weight conversions
  cvt_bf16_kernel<<<512, 256, 0, stream>>>(We_ih, Wihe, (long)2048 * 512);
  cvt_bf16_kernel<<<512, 256, 0, stream>>>(Wr_ih, Wihr, (long)2048 * 512);
  cvt_bf16_kernel<<<1024, 256, 0, stream>>>(Wd_ih, Wihd, (long)4096 * 512);
  cvt_bf16_kernel<<<512, 256, 0, stream>>>(We_hh, Wbf_e, (long)2048 * 512);
  cvt_bf16_kernel<<<512, 256, 0, stream>>>(Wr_hh, Wbf_e + (size_t)2048 * 512, (long)2048 * 512);
  cvt_dec_frag<<<2048, 256, 0, stream>>>(Wd_hh, Wfragd);
  cvt_bf16_kernel<<<32000, 256, 0, stream>>>(W_out, Wobf, (long)NV * 2048);

  // input-gate GEMMs (bf16 MFMA, both biases folded)
  mfma_gemm_bias<<<dim3(16, 16), 256, 0, stream>>>(xsrcb, Wihe, be_ih, be_hh, Aef, 2048, 2048, 512);
  mfma_gemm_bias<<<dim3(16, 16), 256, 0, stream>>>(xsrcb, Wihr, br_ih, br_hh, Aer, 2048, 2048, 512);
  mfma_gemm_bias<<<dim3(16, 32), 256, 0, stream>>>(xtrgb, Wihd, bd_ih, bd_hh, Ad, NR, 4096, 512);

  // full recurrence (fence-free grouped flag barriers)
  recurrence_kernel<<<RECB, 256, 0, stream>>>(Wbf_e, Wfragd, Aef, Aer, Ad, src_lens,
                                              ssb, hs_dec, Ybf, hbf_e, hbf_d, flags);

  // batched attention (compact rows; ctx only feeds logits)
  attn_kernel<<<NR, 256, 0, stream>>>(hs_dec, ssb, src_lens, rowmap, mcnt, Ybf);

  // fused bf16-MFMA logits GEMM + chunked logsumexp (XCD-swizzled, compacted, no-spill)
  gemmlse_mfma<<<4000, 256, 0, stream>>>(Ybf, Wobf, b_out, trg_tokens, rowmap, mcnt, pm, ps, tgtlog);
  lse_combine_kernel<<<(NR + 255) / 256, 256, 0, stream>>>(pm, ps, tgtlog, mcnt, rowval);
  final_reduce_kernel<<<1, 256, 0, stream>>>(rowval, (float*)d_out);
}

// Round 10
// 1293.755 us; speedup vs baseline: 3.0258x; 3.0258x over previous
//
#include <hip/hip_runtime.h>
#include <math.h>

#define NB 32      // batch
#define NS 64      // src len
#define NT 64      // trg len
#define NHD 1024   // dec hidden
#define NV 32000
#define NR 2016    // (NT-1)*NB
#define NCT 250    // 32000/128
#define RECB 64    // blocks in persistent recurrence kernel

typedef unsigned short u16;
typedef __bf16 bf16x8 __attribute__((ext_vector_type(8)));
typedef float f32x4 __attribute__((ext_vector_type(4)));
typedef unsigned u32x4 __attribute__((ext_vector_type(4)));
#define MFMA16 __builtin_amdgcn_mfma_f32_16x16x32_bf16

__device__ __forceinline__ float sigmf(float x) { return 1.f / (1.f + expf(-x)); }
__device__ __forceinline__ u16 f2bf(float f) {
  union { float f; unsigned u; } v; v.f = f;
  unsigned r = v.u + 0x7FFFu + ((v.u >> 16) & 1u);
  return (u16)(r >> 16);
}
__device__ __forceinline__ float bf2f(u16 h) {
  union { unsigned u; float f; } v; v.u = ((unsigned)h) << 16; return v.f;
}

// ---- coherent (cache-bypassing) loads/stores for cross-block data ----
__device__ __forceinline__ u32x4 ldg_coh(const void* p) {
  u32x4 v;
  asm volatile("global_load_dwordx4 %0, %1, off sc0 sc1" : "=v"(v) : "v"(p));
  return v;  // NOT valid until an explicit s_waitcnt vmcnt(0)
}
__device__ __forceinline__ void stg_coh_u32(void* p, unsigned v) {
  asm volatile("global_store_dword %0, %1, off sc0 sc1" :: "v"(p), "v"(v) : "memory");
}
__device__ __forceinline__ unsigned ldg_coh_u32_wait(const void* p) {
  unsigned v;
  asm volatile("global_load_dword %0, %1, off sc0 sc1\n\ts_waitcnt vmcnt(0)"
               : "=v"(v) : "v"(p) : "memory");
  return v;
}
__device__ __forceinline__ void vmwait0() {
  asm volatile("s_waitcnt vmcnt(0)" ::: "memory");
}

__global__ void init_flags_kernel(unsigned* flags) {
  if (threadIdx.x < RECB) flags[threadIdx.x] = 0u;
}

// ---------------- row compaction: valid rows (t+1 < trg_len) -> rowmap ----------------
__global__ void rowmap_kernel(const int* __restrict__ trg_lens,
                              unsigned* __restrict__ rowmap, unsigned* __restrict__ mcnt) {
  __shared__ unsigned P[32];
  int tid = threadIdx.x;
  for (int i = tid; i < 2048; i += 256) rowmap[i] = 0u;
  if (tid == 0) {
    unsigned acc = 0;
    for (int b = 0; b < 32; b++) {
      P[b] = acc;
      int L = trg_lens[b]; if (L > NT) L = NT;
      acc += (unsigned)(L - 1);
    }
    mcnt[0] = acc;
  }
  __syncthreads();
  for (int b = 0; b < 32; b++) {
    int L = trg_lens[b]; if (L > NT) L = NT;
    int Lb = L - 1;
    if (tid < Lb) rowmap[P[b] + tid] = (unsigned)(tid * 32 + b);
  }
}

// ---------------- gathers (emit bf16) ----------------
__global__ void gather_src_bf16(const int* tok, const float* emb, u16* out) {
  int idx = blockIdx.x * 256 + threadIdx.x;  // 2048*64
  if (idx >= 2048 * 64) return;
  int m = idx >> 6, c8 = (idx & 63) * 8;
  const float4* s = (const float4*)(emb + (size_t)tok[m] * 512 + c8);
  float4 a = s[0], b = s[1];
  union { u16 h[8]; uint4 v; } u;
  u.h[0]=f2bf(a.x); u.h[1]=f2bf(a.y); u.h[2]=f2bf(a.z); u.h[3]=f2bf(a.w);
  u.h[4]=f2bf(b.x); u.h[5]=f2bf(b.y); u.h[6]=f2bf(b.z); u.h[7]=f2bf(b.w);
  *(uint4*)(out + (size_t)m * 512 + c8) = u.v;
}

__global__ void gather_trg_bf16(const int* tok, const float* emb, u16* out) {
  int idx = blockIdx.x * 256 + threadIdx.x;  // NR*64
  if (idx >= NR * 64) return;
  int m = idx >> 6, c8 = (idx & 63) * 8;
  int t = m >> 5, b = m & 31;  // row m = t*32 + b
  int token = tok[b * NT + t];
  const float4* s = (const float4*)(emb + (size_t)token * 512 + c8);
  float4 a = s[0], bb = s[1];
  union { u16 h[8]; uint4 v; } u;
  u.h[0]=f2bf(a.x); u.h[1]=f2bf(a.y); u.h[2]=f2bf(a.z); u.h[3]=f2bf(a.w);
  u.h[4]=f2bf(bb.x); u.h[5]=f2bf(bb.y); u.h[6]=f2bf(bb.z); u.h[7]=f2bf(bb.w);
  *(uint4*)(out + (size_t)m * 512 + c8) = u.v;
}

// ---------------- f32 -> bf16 ----------------
__global__ void cvt_bf16_kernel(const float* __restrict__ in, u16* __restrict__ out, long n) {
  long i = ((long)blockIdx.x * 256 + threadIdx.x) * 8;
  if (i >= n) return;
  float4 a = *(const float4*)(in + i);
  float4 b = *(const float4*)(in + i + 4);
  union { u16 h[8]; uint4 v; } u;
  u.h[0]=f2bf(a.x); u.h[1]=f2bf(a.y); u.h[2]=f2bf(a.z); u.h[3]=f2bf(a.w);
  u.h[4]=f2bf(b.x); u.h[5]=f2bf(b.y); u.h[6]=f2bf(b.z); u.h[7]=f2bf(b.w);
  *(uint4*)(out + i) = u.v;
}

// ---------------- dec W -> bf16 fragment layout ----------------
__global__ void cvt_dec_frag(const float* __restrict__ W, u16* __restrict__ out) {
  int idx = blockIdx.x * 256 + threadIdx.x;  // 524288 chunks
  if (idx >= 64 * 4 * 32 * 64) return;
  int lane = idx & 63;
  int kk = (idx >> 6) & 31;
  int g = (idx >> 11) & 3;
  int jt = idx >> 13;
  int row = g * 1024 + jt * 16 + (lane & 15);
  int col = kk * 32 + (lane >> 4) * 8;
  const float4* s = (const float4*)(W + (size_t)row * NHD + col);
  float4 a = s[0], b = s[1];
  union { u16 h[8]; uint4 v; } u;
  u.h[0]=f2bf(a.x); u.h[1]=f2bf(a.y); u.h[2]=f2bf(a.z); u.h[3]=f2bf(a.w);
  u.h[4]=f2bf(b.x); u.h[5]=f2bf(b.y); u.h[6]=f2bf(b.z); u.h[7]=f2bf(b.w);
  *(uint4*)(out + (size_t)idx * 8) = u.v;
}

// ---------------- W_out -> bf16 fragment layout ----------------
// chunk idx = (j16*64 + kk)*64 + lane ; holds W_out[j16*16 + (lane&15)][kk*32 + (lane>>4)*8 ..+8]
__global__ void cvt_wo_frag(const float* __restrict__ W, u16* __restrict__ out) {
  long idx = (long)blockIdx.x * 256 + threadIdx.x;  // 2000*64*64 = 8,192,000 chunks
  if (idx >= (long)2000 * 64 * 64) return;
  int lane = (int)(idx & 63);
  int kk = (int)((idx >> 6) & 63);
  long j16 = idx >> 12;
  long row = j16 * 16 + (lane & 15);
  int col = kk * 32 + (lane >> 4) * 8;
  const float4* s = (const float4*)(W + (size_t)row * 2048 + col);
  float4 a = s[0], b = s[1];
  union { u16 h[8]; uint4 v; } u;
  u.h[0]=f2bf(a.x); u.h[1]=f2bf(a.y); u.h[2]=f2bf(a.z); u.h[3]=f2bf(a.w);
  u.h[4]=f2bf(b.x); u.h[5]=f2bf(b.y); u.h[6]=f2bf(b.z); u.h[7]=f2bf(b.w);
  *(uint4*)(out + (size_t)idx * 8) = u.v;
}

// ---------------- Ybf -> fragment layout (rowmap folded in) ----------------
// chunk idx = (im*64 + kk)*64 + lane ; holds Ybf[rowmap[im*16+(lane&15)]][kk*32+(lane>>4)*8..+8]
__global__ void yfrag_repack(const u16* __restrict__ Ybf, const unsigned* __restrict__ rowmap,
                             u16* __restrict__ out) {
  int idx = blockIdx.x * 256 + threadIdx.x;  // 128*64*64 = 524288 chunks
  if (idx >= 128 * 64 * 64) return;
  int lane = idx & 63;
  int kk = (idx >> 6) & 63;
  int im = idx >> 12;
  int rr = (int)rowmap[im * 16 + (lane & 15)];  // invalid rows -> 0 (always initialized)
  int col = kk * 32 + (lane >> 4) * 8;
  *(uint4*)(out + (size_t)idx * 8) = *(const uint4*)(Ybf + (size_t)rr * 2048 + col);
}

// ---------------- bf16 MFMA GEMM for input gates (direct-global) ----------------
__global__ __launch_bounds__(256) void mfma_gemm_bias(
    const u16* __restrict__ A, const u16* __restrict__ Bm,
    const float* __restrict__ b0, const float* __restrict__ b1,
    float* __restrict__ C, int M, int N, int K) {
  int tid = threadIdx.x, wave = tid >> 6, lane = tid & 63;
  int r = lane & 15, q = lane >> 4;
  int mh = wave >> 1, nh = wave & 1;
  int rowbase = blockIdx.x * 128 + mh * 64;
  int colbase = blockIdx.y * 128 + nh * 64;
  f32x4 acc[4][4] = {};
  for (int k0 = 0; k0 < K; k0 += 32) {
    bf16x8 a[4], b[4];
#pragma unroll
    for (int mt = 0; mt < 4; mt++) {
      int rb = rowbase + mt * 16 + r;
      if (rb >= M) rb = 0;
      a[mt] = *(const bf16x8*)(A + (size_t)rb * K + k0 + q * 8);
    }
#pragma unroll
    for (int nt = 0; nt < 4; nt++)
      b[nt] = *(const bf16x8*)(Bm + (size_t)(colbase + nt * 16 + r) * K + k0 + q * 8);
#pragma unroll
    for (int mt = 0; mt < 4; mt++)
#pragma unroll
      for (int nt = 0; nt < 4; nt++)
        acc[mt][nt] = MFMA16(a[mt], b[nt], acc[mt][nt], 0, 0, 0);
  }
#pragma unroll
  for (int nt = 0; nt < 4; nt++) {
    int gn = colbase + nt * 16 + r;
    float bb = b0[gn] + b1[gn];
#pragma unroll
    for (int mt = 0; mt < 4; mt++)
#pragma unroll
      for (int j = 0; j < 4; j++) {
        int gm = rowbase + mt * 16 + q * 4 + j;
        if (gm < M) C[(size_t)gm * N + gn] = acc[mt][nt][j] + bb;
      }
  }
}

// ---------------- persistent recurrence (fence-free flag barrier, grouped) ----------------
#define ENC_H_OFF 65536
#define ENC_G_OFF 98304
#define DEC_G_OFF 65536
__global__ __launch_bounds__(256, 1) void recurrence_kernel(
    const u16* __restrict__ Wbf_e,    // [4096][512] (fwd 0..2047, rev 2048..)
    const u16* __restrict__ Wfragd,   // dec W fragment layout, 8MB
    const float* __restrict__ Aef, const float* __restrict__ Aer, const float* __restrict__ Ad,
    const int* __restrict__ src_lens,
    u16* __restrict__ ssb, float* __restrict__ hs_dec, u16* __restrict__ Ybf,
    u16* __restrict__ hbf_e,   // [2 parity][2 lstm][32][512] bf16 (coherent)
    u16* __restrict__ hbf_d,   // [2 parity][32][1024] bf16 (coherent)
    unsigned* flags) {
  __shared__ __align__(16) char smem[107008];
  const int tid = threadIdx.x, bid = blockIdx.x;
  const int wave = tid >> 6, lane = tid & 63;
  const int r = lane & 15, q = lane >> 4;
  const int g = wave;
  const int ob = tid >> 3;        // epilogue batch
  const int oj = (tid & 7) * 2;   // epilogue col pair within 16
  const int slen_ob = src_lens[ob];
  unsigned tgt = 0;

  // group barrier: this block signals flags[bid], waits on flags[fbase..fbase+fcnt)
#define FLAGBAR(fbase, fcnt)                                                        \
  do {                                                                              \
    tgt++;                                                                          \
    vmwait0();                                                                      \
    __syncthreads();                                                                \
    if (wave == 0) {                                                                \
      if (lane == 0) stg_coh_u32(flags + bid, tgt);                                 \
      unsigned fv = tgt;                                                            \
      do {                                                                          \
        if (lane < (fcnt)) fv = ldg_coh_u32_wait(flags + (fbase) + lane);           \
      } while (__any(fv < tgt));                                                    \
    }                                                                               \
    __syncthreads();                                                                \
  } while (0)

  // ================= encoder =================
  {
    const int lstm = bid >> 5, jt = bid & 31;
    float* gates = (float*)(smem + ENC_G_OFF);
    for (int c = tid; c < 64 * 64; c += 256) {
      int lr = c >> 6, c8 = (c & 63) * 8;
      int grow = lstm * 2048 + (lr >> 4) * 512 + jt * 16 + (lr & 15);
      uint4 v = *(const uint4*)(Wbf_e + (size_t)grow * 512 + c8);
      *(uint4*)(smem + ((lr * 1024 + c8 * 2) ^ ((lr & 7) << 4))) = v;
    }
    const float* Ae = lstm ? Aer : Aef;
    const int jcol = jt * 16 + oj;
    float creg0 = 0.f, creg1 = 0.f;
    for (int t = 0; t < NS; t++) {
      size_t abase = ((size_t)ob * NS + t) * 2048;
      float2 vi = *(const float2*)(Ae + abase + jcol);
      float2 vf = *(const float2*)(Ae + abase + 512 + jcol);
      float2 vg = *(const float2*)(Ae + abase + 1024 + jcol);
      float2 vo = *(const float2*)(Ae + abase + 1536 + jcol);
      if (t == 0) {
        u32x4 z = {0u, 0u, 0u, 0u};
#pragma unroll
        for (int k = 0; k < 8; k++) {
          int c = tid + k * 256;
          int hr = c >> 6, seg = c & 63;
          *(u32x4*)(smem + (ENC_H_OFF + ((hr * 1024 + seg * 16) ^ ((hr & 7) << 4)))) = z;
        }
      } else {
        const u16* hsrc = hbf_e + ((size_t)(t & 1) * 2 + lstm) * 16384;
        u32x4 hv[8];
#pragma unroll
        for (int k = 0; k < 8; k++) hv[k] = ldg_coh(hsrc + (tid + k * 256) * 8);
        vmwait0();
#pragma unroll
        for (int k = 0; k < 8; k++) {
          int c = tid + k * 256;
          int hr = c >> 6, seg = c & 63;
          *(u32x4*)(smem + (ENC_H_OFF + ((hr * 1024 + seg * 16) ^ ((hr & 7) << 4)))) = hv[k];
        }
      }
      __syncthreads();
      f32x4 acc0 = {0.f,0.f,0.f,0.f}, acc1 = {0.f,0.f,0.f,0.f};
      for (int ks = 0; ks < 512; ks += 32) {
        int col2 = (ks + q * 8) * 2;
        int a0r = r, a1r = 16 + r, br = g * 16 + r;
        bf16x8 a0 = *(const bf16x8*)(smem + (ENC_H_OFF + ((a0r * 1024 + col2) ^ ((a0r & 7) << 4))));
        bf16x8 a1 = *(const bf16x8*)(smem + (ENC_H_OFF + ((a1r * 1024 + col2) ^ ((a1r & 7) << 4))));
        bf16x8 bf = *(const bf16x8*)(smem + ((br * 1024 + col2) ^ ((br & 7) << 4)));
        acc0 = MFMA16(a0, bf, acc0, 0, 0, 0);
        acc1 = MFMA16(a1, bf, acc1, 0, 0, 0);
      }
#pragma unroll
      for (int j = 0; j < 4; j++) {
        gates[(g * 32 + q * 4 + j) * 17 + r] = acc0[j];
        gates[(g * 32 + 16 + q * 4 + j) * 17 + r] = acc1[j];
      }
      __syncthreads();
      {
        float I0 = vi.x + gates[(0 * 32 + ob) * 17 + oj];
        float I1 = vi.y + gates[(0 * 32 + ob) * 17 + oj + 1];
        float F0 = vf.x + gates[(1 * 32 + ob) * 17 + oj];
        float F1 = vf.y + gates[(1 * 32 + ob) * 17 + oj + 1];
        float G0 = vg.x + gates[(2 * 32 + ob) * 17 + oj];
        float G1 = vg.y + gates[(2 * 32 + ob) * 17 + oj + 1];
        float O0 = vo.x + gates[(3 * 32 + ob) * 17 + oj];
        float O1 = vo.y + gates[(3 * 32 + ob) * 17 + oj + 1];
        float c0 = sigmf(F0) * creg0 + sigmf(I0) * tanhf(G0);
        float c1 = sigmf(F1) * creg1 + sigmf(I1) * tanhf(G1);
        float h0 = sigmf(O0) * tanhf(c0);
        float h1 = sigmf(O1) * tanhf(c1);
        creg0 = c0; creg1 = c1;
        unsigned hv2 = ((unsigned)f2bf(h1) << 16) | f2bf(h0);
        stg_coh_u32(hbf_e + ((size_t)((t + 1) & 1) * 2 + lstm) * 16384 + ob * 512 + jcol, hv2);
        *(unsigned*)(ssb + ((size_t)ob * NS + t) * NHD + lstm * 512 + jcol) = hv2;
        if (t == slen_ob - 1)
          stg_coh_u32(hbf_d + ob * NHD + lstm * 512 + jcol, hv2);
      }
      FLAGBAR(lstm * 32, 32);  // enc blocks only depend on same-lstm peers
    }
  }

  // phase barrier: all encoder output (hbf_d) visible to every block
  FLAGBAR(0, RECB);

  // ================= decoder =================
  {
    const int jt = bid;
    const int jcol = jt * 16 + oj;
    float* gates = (float*)(smem + DEC_G_OFF);
    const u16* wbase = Wfragd + (size_t)(jt * 4 + g) * 16384;
    float cd0 = 0.f, cd1 = 0.f;
    for (int t = 0; t < NT - 1; t++) {
      const float* ad = Ad + ((size_t)t * NB + ob) * 4096;
      float2 vi = *(const float2*)(ad + jcol);
      float2 vf = *(const float2*)(ad + 1024 + jcol);
      float2 vg = *(const float2*)(ad + 2048 + jcol);
      float2 vo = *(const float2*)(ad + 3072 + jcol);
      const u16* hsrc = hbf_d + (size_t)(t & 1) * (32 * NHD);
      {
        u32x4 hv[16];
#pragma unroll
        for (int k = 0; k < 16; k++) hv[k] = ldg_coh(hsrc + (tid + k * 256) * 8);
        vmwait0();
#pragma unroll
        for (int k = 0; k < 16; k++) {
          int c = tid + k * 256;
          int hr = c >> 7, seg = c & 127;
          *(u32x4*)(smem + ((hr * 2048 + seg * 16) ^ ((hr & 7) << 4))) = hv[k];
        }
      }
      __syncthreads();
      f32x4 acc0 = {0.f,0.f,0.f,0.f}, acc1 = {0.f,0.f,0.f,0.f};
      for (int kk = 0; kk < 32; kk++) {
        int colb = (kk * 32 + q * 8) * 2;
        int a0r = r, a1r = 16 + r;
        bf16x8 a0 = *(const bf16x8*)(smem + ((a0r * 2048 + colb) ^ ((a0r & 7) << 4)));
        bf16x8 a1 = *(const bf16x8*)(smem + ((a1r * 2048 + colb) ^ ((a1r & 7) << 4)));
        bf16x8 bf = *(const bf16x8*)(wbase + ((size_t)kk * 64 + lane) * 8);
        acc0 = MFMA16(a0, bf, acc0, 0, 0, 0);
        acc1 = MFMA16(a1, bf, acc1, 0, 0, 0);
      }
#pragma unroll
      for (int j = 0; j < 4; j++) {
        gates[(g * 32 + q * 4 + j) * 17 + r] = acc0[j];
        gates[(g * 32 + 16 + q * 4 + j) * 17 + r] = acc1[j];
      }
      __syncthreads();
      {
        float I0 = vi.x + gates[(0 * 32 + ob) * 17 + oj];
        float I1 = vi.y + gates[(0 * 32 + ob) * 17 + oj + 1];
        float F0 = vf.x + gates[(1 * 32 + ob) * 17 + oj];
        float F1 = vf.y + gates[(1 * 32 + ob) * 17 + oj + 1];
        float G0 = vg.x + gates[(2 * 32 + ob) * 17 + oj];
        float G1 = vg.y + gates[(2 * 32 + ob) * 17 + oj + 1];
        float O0 = vo.x + gates[(3 * 32 + ob) * 17 + oj];
        float O1 = vo.y + gates[(3 * 32 + ob) * 17 + oj + 1];
        float c0 = sigmf(F0) * cd0 + sigmf(I0) * tanhf(G0);
        float c1 = sigmf(F1) * cd1 + sigmf(I1) * tanhf(G1);
        float h0 = sigmf(O0) * tanhf(c0);
        float h1 = sigmf(O1) * tanhf(c1);
        cd0 = c0; cd1 = c1;
        size_t rowY = (size_t)t * NB + ob;
        unsigned hv2 = ((unsigned)f2bf(h1) << 16) | f2bf(h0);
        stg_coh_u32(hbf_d + (size_t)((t + 1) & 1) * (32 * NHD) + ob * NHD + jcol, hv2);
        *(unsigned*)(Ybf + rowY * 2048 + jcol) = hv2;
        float2 hvf; hvf.x = h0; hvf.y = h1;
        *(float2*)(hs_dec + rowY * NHD + jcol) = hvf;
      }
      if (t != NT - 2) FLAGBAR(0, RECB);
    }
  }
#undef FLAGBAR
}

// ---------------- batched attention (bf16 src states, compact rows) ----------------
__global__ __launch_bounds__(256) void attn_kernel(const float* __restrict__ hs,
                                                   const u16* __restrict__ ssb,
                                                   const int* __restrict__ src_lens,
                                                   const unsigned* __restrict__ rowmap,
                                                   const unsigned* __restrict__ mcnt,
                                                   u16* __restrict__ Ybf) {
  __shared__ __align__(16) float hsh[NHD];
  __shared__ float sc[NS];
  __shared__ float att[NS];
  int cr = blockIdx.x;
  if ((unsigned)cr >= mcnt[0]) return;
  int rr = (int)rowmap[cr];
  int b = rr & 31;
  int tid = threadIdx.x;
  for (int i = tid; i < NHD; i += 256) hsh[i] = hs[(size_t)rr * NHD + i];
  __syncthreads();
  {
    int s = tid >> 2, q = tid & 3;
    const u16* row = ssb + ((size_t)b * NS + s) * NHD + q * 256;
    const float* h4 = hsh + q * 256;
    float p = 0.f;
    for (int k = 0; k < 256; k += 8) {
      uint4 v = *(const uint4*)(row + k);
      p += h4[k + 0] * bf2f((u16)(v.x & 0xFFFF)) + h4[k + 1] * bf2f((u16)(v.x >> 16));
      p += h4[k + 2] * bf2f((u16)(v.y & 0xFFFF)) + h4[k + 3] * bf2f((u16)(v.y >> 16));
      p += h4[k + 4] * bf2f((u16)(v.z & 0xFFFF)) + h4[k + 5] * bf2f((u16)(v.z >> 16));
      p += h4[k + 6] * bf2f((u16)(v.w & 0xFFFF)) + h4[k + 7] * bf2f((u16)(v.w >> 16));
    }
    p += __shfl_xor(p, 1);
    p += __shfl_xor(p, 2);
    if (q == 0) sc[s] = (s < src_lens[b]) ? p : -1e9f;
  }
  __syncthreads();
  if (tid < 64) {
    float v = sc[tid];
    float m = v;
#pragma unroll
    for (int off = 1; off < 64; off <<= 1) m = fmaxf(m, __shfl_xor(m, off));
    float e = expf(v - m);
    float ssum = e;
#pragma unroll
    for (int off = 1; off < 64; off <<= 1) ssum += __shfl_xor(ssum, off);
    att[tid] = e / ssum;
  }
  __syncthreads();
  float a0 = 0, a1 = 0, a2 = 0, a3 = 0;
  int d = tid * 4;
  for (int s2 = 0; s2 < NS; s2++) {
    float a = att[s2];
    uint2 v = *(const uint2*)(ssb + ((size_t)b * NS + s2) * NHD + d);
    a0 += a * bf2f((u16)(v.x & 0xFFFF));
    a1 += a * bf2f((u16)(v.x >> 16));
    a2 += a * bf2f((u16)(v.y & 0xFFFF));
    a3 += a * bf2f((u16)(v.y >> 16));
  }
  ushort4 o;
  o.x = f2bf(a0); o.y = f2bf(a1); o.z = f2bf(a2); o.w = f2bf(a3);
  *(ushort4*)(Ybf + (size_t)rr * 2048 + NHD + d) = o;
}

// ---------------- MFMA logits GEMM (fragment-layout operands, fully-coalesced loads) + fused LSE ----------------
// 1D grid 4000 = 16 row-tiles x 250 col-tiles (XCD-grouped); blocks past M_valid exit early.
// Both operands pre-packed in MFMA fragment order: each wave-load = one contiguous 1KB burst
// (vs 16-way 64B scatter of the row-major direct loads).
__global__ __launch_bounds__(256) void gemmlse_mfma(
    const u16* __restrict__ Yf,   // Yfrag: [128 m-tiles][64 kk][64 lanes][8]
    const u16* __restrict__ Wf,   // Wofrag: [2000 n-tiles][64 kk][64 lanes][8]
    const float* __restrict__ bo, const int* __restrict__ trg_tok,
    const unsigned* __restrict__ rowmap, const unsigned* __restrict__ mcnt,
    float* __restrict__ pm, float* __restrict__ ps, float* __restrict__ tgtlog) {
  __shared__ int tgtc[128];
  __shared__ float pmp[2][128];
  __shared__ float psp[2][128];
  int o = blockIdx.x;
  int u = (o & 7) * 500 + (o >> 3);
  int bm = u & 15, bn = u >> 4;
  const int M = (int)mcnt[0];
  if (bm * 128 >= M) return;   // compacted: skip fully-masked row tiles
  int tid = threadIdx.x;
  int wave = tid >> 6, lane = tid & 63;
  int r = lane & 15, q = lane >> 4;
  int mh = wave >> 1, nh = wave & 1;
  if (tid < 128) {
    int gm = bm * 128 + tid;
    if (gm < M) {
      int rr = (int)rowmap[gm];
      int tt = rr >> 5, b = rr & 31;
      tgtc[tid] = trg_tok[b * NT + tt + 1];
    } else {
      tgtc[tid] = -1;
    }
  }
  __syncthreads();
  // fragment base pointers: per-wave m-tiles (bm*8 + mh*4 + mt), n-tiles (bn*8 + nh*4 + nt)
  const u16* ybase = Yf + (((size_t)(bm * 8 + mh * 4) * 64) * 64 + lane) * 8;
  const u16* wbase = Wf + (((size_t)(bn * 8 + nh * 4) * 64) * 64 + lane) * 8;
  f32x4 acc[4][4] = {};
  for (int kk = 0; kk < 64; kk += 2) {
    bf16x8 aA[4], bA[4], aB[4], bB[4];
#pragma unroll
    for (int mt = 0; mt < 4; mt++) {
      const u16* p = ybase + ((size_t)mt * 64 + kk) * 512;
      aA[mt] = *(const bf16x8*)(p);
      aB[mt] = *(const bf16x8*)(p + 512);
    }
#pragma unroll
    for (int nt = 0; nt < 4; nt++) {
      const u16* p = wbase + ((size_t)nt * 64 + kk) * 512;
      bA[nt] = *(const bf16x8*)(p);
      bB[nt] = *(const bf16x8*)(p + 512);
    }
#pragma unroll
    for (int mt = 0; mt < 4; mt++)
#pragma unroll
      for (int nt = 0; nt < 4; nt++)
        acc[mt][nt] = MFMA16(aA[mt], bA[nt], acc[mt][nt], 0, 0, 0);
#pragma unroll
    for (int mt = 0; mt < 4; mt++)
#pragma unroll
      for (int nt = 0; nt < 4; nt++)
        acc[mt][nt] = MFMA16(aB[mt], bB[nt], acc[mt][nt], 0, 0, 0);
  }
  // bias
  int colbase = bn * 128 + nh * 64;
  float bo4[4];
#pragma unroll
  for (int nt = 0; nt < 4; nt++) bo4[nt] = bo[colbase + nt * 16 + r];
#pragma unroll
  for (int mt = 0; mt < 4; mt++)
#pragma unroll
    for (int nt = 0; nt < 4; nt++)
#pragma unroll
      for (int j = 0; j < 4; j++) acc[mt][nt][j] += bo4[nt];
  // in-register row-wise lse over this wave's 64 cols + target capture
#pragma unroll
  for (int mt = 0; mt < 4; mt++) {
#pragma unroll
    for (int j = 0; j < 4; j++) {
      float m = fmaxf(fmaxf(acc[mt][0][j], acc[mt][1][j]), fmaxf(acc[mt][2][j], acc[mt][3][j]));
      m = fmaxf(m, __shfl_xor(m, 1));
      m = fmaxf(m, __shfl_xor(m, 2));
      m = fmaxf(m, __shfl_xor(m, 4));
      m = fmaxf(m, __shfl_xor(m, 8));
      float s = expf(acc[mt][0][j] - m) + expf(acc[mt][1][j] - m) +
                expf(acc[mt][2][j] - m) + expf(acc[mt][3][j] - m);
      s += __shfl_xor(s, 1);
      s += __shfl_xor(s, 2);
      s += __shfl_xor(s, 4);
      s += __shfl_xor(s, 8);
      int lrow = mh * 64 + mt * 16 + q * 4 + j;
      if (r == 0) { pmp[nh][lrow] = m; psp[nh][lrow] = s; }
      int tc = tgtc[lrow];
      int off = tc - (bn * 128 + nh * 64);
      if (off >= 0 && off < 64 && (off & 15) == r) {
        tgtlog[bm * 128 + lrow] = acc[mt][off >> 4][j];
      }
    }
  }
  __syncthreads();
  if (tid < 128) {
    int gm = bm * 128 + tid;
    if (gm < M) {
      float m0 = pmp[0][tid], m1 = pmp[1][tid];
      float m = fmaxf(m0, m1);
      float s = psp[0][tid] * expf(m0 - m) + psp[1][tid] * expf(m1 - m);
      pm[(size_t)bn * NR + gm] = m;
      ps[(size_t)bn * NR + gm] = s;
    }
  }
}

// ---------------- merge per-chunk lse partials (compact rows) ----------------
__global__ void lse_combine_kernel(const float* __restrict__ pm, const float* __restrict__ ps,
                                   const float* __restrict__ tgtlog,
                                   const unsigned* __restrict__ mcnt,
                                   float* __restrict__ rowval) {
  int cr = blockIdx.x * blockDim.x + threadIdx.x;
  if (cr >= NR) return;
  if ((unsigned)cr >= mcnt[0]) { rowval[cr] = 0.f; return; }
  float m = -1e30f;
  for (int i = 0; i < NCT; i++) m = fmaxf(m, pm[(size_t)i * NR + cr]);
  float s = 0.f;
  for (int i = 0; i < NCT; i++) s += ps[(size_t)i * NR + cr] * expf(pm[(size_t)i * NR + cr] - m);
  float lse = m + logf(s);
  rowval[cr] = tgtlog[cr] - lse;
}

__global__ void final_reduce_kernel(const float* __restrict__ rowval, float* __restrict__ out) {
  __shared__ float sm[256];
  float s = 0.f;
  for (int i = threadIdx.x; i < NR; i += 256) s += rowval[i];
  sm[threadIdx.x] = s;
  __syncthreads();
  for (int off = 128; off > 0; off >>= 1) {
    if (threadIdx.x < off) sm[threadIdx.x] += sm[threadIdx.x + off];
    __syncthreads();
  }
  if (threadIdx.x == 0) out[0] = sm[0];
}

extern "C" void kernel_launch(void* const* d_in, const int* in_sizes, int n_in,
                              void* d_out, int out_size, void* d_ws, size_t ws_size,
                              hipStream_t stream) {
  const int* src_tokens = (const int*)d_in[0];
  const int* src_lens = (const int*)d_in[1];
  const int* trg_tokens = (const int*)d_in[2];
  const int* trg_lens = (const int*)d_in[3];
  const float* src_emb = (const float*)d_in[4];
  const float* trg_emb = (const float*)d_in[5];
  const float* We_ih = (const float*)d_in[6];
  const float* We_hh = (const float*)d_in[7];
  const float* be_ih = (const float*)d_in[8];
  const float* be_hh = (const float*)d_in[9];
  const float* Wr_ih = (const float*)d_in[10];
  const float* Wr_hh = (const float*)d_in[11];
  const float* br_ih = (const float*)d_in[12];
  const float* br_hh = (const float*)d_in[13];
  const float* Wd_ih = (const float*)d_in[14];
  const float* Wd_hh = (const float*)d_in[15];
  const float* bd_ih = (const float*)d_in[16];
  const float* bd_hh = (const float*)d_in[17];
  const float* W_out = (const float*)d_in[18];
  const float* b_out = (const float*)d_in[19];

  char* base = (char*)d_ws;
  size_t off = 0;
  auto alloc = [&](size_t bytes) -> char* {
    char* p = base + off;
    off += (bytes + 255) & ~(size_t)255;
    return p;
  };
  u16* xsrcb = (u16*)alloc((size_t)2048 * 512 * 2);
  u16* xtrgb = (u16*)alloc((size_t)NR * 512 * 2);
  u16* Wihe = (u16*)alloc((size_t)2048 * 512 * 2);
  u16* Wihr = (u16*)alloc((size_t)2048 * 512 * 2);
  u16* Wihd = (u16*)alloc((size_t)4096 * 512 * 2);
  u16* Wbf_e = (u16*)alloc((size_t)4096 * 512 * 2);
  u16* Wfragd = (u16*)alloc((size_t)4096 * 1024 * 2);
  u16* Wofrag = (u16*)alloc((size_t)NV * 2048 * 2);
  u16* Yfrag = (u16*)alloc((size_t)128 * 64 * 64 * 8 * 2);
  float* Aef = (float*)alloc((size_t)2048 * 2048 * 4);
  float* Aer = (float*)alloc((size_t)2048 * 2048 * 4);
  float* Ad  = (float*)alloc((size_t)NR * 4096 * 4);
  u16* ssb  = (u16*)alloc((size_t)NB * NS * NHD * 2);
  float* hs_dec = (float*)alloc((size_t)NR * NHD * 4);
  u16* Ybf = (u16*)alloc((size_t)NR * 2048 * 2);
  u16* hbf_e = (u16*)alloc((size_t)4 * 32 * 512 * 2);
  u16* hbf_d = (u16*)alloc((size_t)2 * 32 * NHD * 2);
  float* pm = (float*)alloc((size_t)NCT * NR * 4);
  float* ps = (float*)alloc((size_t)NCT * NR * 4);
  float* tgtlog = (float*)alloc((size_t)NR * 4);
  float* rowval = (float*)alloc((size_t)NR * 4);
  unsigned* flags = (unsigned*)alloc(256);
  unsigned* rowmap = (unsigned*)alloc(2048 * 4);
  unsigned* mcnt = (unsigned*)alloc(256);

  init_flags_kernel<<<1, 64, 0, stream>>>(flags);
  rowmap_kernel<<<1, 256, 0, stream>>>(trg_lens, rowmap, mcnt);

  // gathers (bf16 out)
  gather_src_bf16<<<512, 256, 0, stream>>>(src_tokens, src_emb, xsrcb);
  gather_trg_bf16<<<(NR * 64 + 255) / 256, 256, 0, stream>>>(trg_tokens, trg_emb, xtrgb);

  // weight conversions
  cvt_bf16_kernel<<<512, 256, 0, stream>>>(We_ih, Wihe, (long)2048 * 512);
  cvt_bf16_kernel<<<512, 256, 0, stream>>>(Wr_ih, Wihr, (long)2048 * 512);
  cvt_bf16_kernel<<<1024, 256, 0, stream>>>(Wd_ih, Wihd, (long)4096 * 512);
  cvt_bf16_kernel<<<512, 256, 0, stream>>>(We_hh, Wbf_e, (long)2048 * 512);
  cvt_bf16_kernel<<<512, 256, 0, stream>>>(Wr_hh, Wbf_e + (size_t)2048 * 512, (long)2048 * 512);
  cvt_dec_frag<<<2048, 256, 0, stream>>>(Wd_hh, Wfragd);
  cvt_wo_frag<<<32000, 256, 0, stream>>>(W_out, Wofrag);

  // input-gate GEMMs (bf16 MFMA, both biases folded)
  mfma_gemm_bias<<<dim3(16, 16), 256, 0, stream>>>(xsrcb, Wihe, be_ih, be_hh, Aef, 2048, 2048, 512);
  mfma_gemm_bias<<<dim3(16, 16), 256, 0, stream>>>(xsrcb, Wihr, br_ih, br_hh, Aer, 2048, 2048, 512);
  mfma_gemm_bias<<<dim3(16, 32), 256, 0, stream>>>(xtrgb, Wihd, bd_ih, bd_hh, Ad, NR, 4096, 512);

  // full recurrence (fence-free grouped flag barriers)
  recurrence_kernel<<<RECB, 256, 0, stream>>>(Wbf_e, Wfragd, Aef, Aer, Ad, src_lens,
                                              ssb, hs_dec, Ybf, hbf_e, hbf_d, flags);

  // batched attention (compact rows; ctx only feeds logits)
  attn_kernel<<<NR, 256, 0, stream>>>(hs_dec, ssb, src_lens, rowmap, mcnt, Ybf);

  // repack Y into fragment layout (rowmap folded in)
  yfrag_repack<<<2048, 256, 0, stream>>>(Ybf, rowmap, Yfrag);

  // fused bf16-MFMA logits GEMM + chunked logsumexp (fragment operands, XCD-swizzled, compacted)
  gemmlse_mfma<<<4000, 256, 0, stream>>>(Yfrag, Wofrag, b_out, trg_tokens, rowmap, mcnt, pm, ps, tgtlog);
  lse_combine_kernel<<<(NR + 255) / 256, 256, 0, stream>>>(pm, ps, tgtlog, mcnt, rowval);
  final_reduce_kernel<<<1, 256, 0, stream>>>(rowval, (float*)d_out);
}